// Round 1
// baseline (93.169 us; speedup 1.0000x reference)
//
#include <hip/hip_runtime.h>
#include <math.h>

// RBF pairwise kernel: out[i,j] = var * exp(-0.5 * sum_d ((x[i,d]-xx[j,d])/s[d])^2)
// N=M=4096, D=16, fp32 in/out.
//
// Layout choice (the whole game is keeping stores coalesced and LDS conflict-free):
//   - grid = (M/256, N/64), block = 256 threads = 4 waves.
//   - Block tile: 64 i-rows x 256 j-cols.
//   - j varies across LANES: lane l owns j = j0 + 4l .. 4l+3  -> float4 stores,
//     64 lanes write 1024 contiguous bytes per store (fully coalesced).
//   - i is WAVE-UNIFORM: wave w owns i-rows [i0+16w, i0+16w+16). The x-row
//     fragment is read from LDS at one address for all 64 lanes -> broadcast,
//     zero bank conflicts.
//   - Each thread keeps its 4 xx rows (pre-scaled) in 64 VGPRs for the whole
//     block -> 1 broadcast ds_read_b128 per 4 outputs, 32 VALU per output.

#define NN 4096
#define MM 4096
#define DD 16

__global__ __launch_bounds__(256, 4)
void rbf_kernel(const float* __restrict__ x, const float* __restrict__ xx,
                const float* __restrict__ scale_ff,
                const float* __restrict__ variance_ff,
                float* __restrict__ out) {
  __shared__ __align__(16) float s_inv[DD];   // 1/softplus(scale_ff)
  __shared__ float s_var;                     // softplus(variance_ff)
  __shared__ __align__(16) float s_x[64 * DD]; // pre-scaled x tile (64 rows)

  const int tid  = threadIdx.x;
  const int lane = tid & 63;
  const int wave = tid >> 6;

  const int i0 = blockIdx.y * 64;
  const int j0 = blockIdx.x * 256;

  // softplus params (once per block; precise libm, cost is negligible)
  if (tid < DD) {
    s_inv[tid] = 1.0f / log1pf(expf(scale_ff[tid]));
  }
  if (tid == DD) {
    s_var = log1pf(expf(variance_ff[0]));
  }
  __syncthreads();

  // Stage the 64-row x tile into LDS, pre-scaled. 256 threads x 1 float4 each;
  // global reads are fully coalesced (16 KB contiguous... 4 KB here).
  {
    const int row = tid >> 2;
    const int c   = tid & 3;
    float4 xv = *(const float4*)&x[(i0 + row) * DD + c * 4];
    float4 iv = *(const float4*)&s_inv[c * 4];
    xv.x *= iv.x; xv.y *= iv.y; xv.z *= iv.z; xv.w *= iv.w;
    *(float4*)&s_x[row * DD + c * 4] = xv;
  }

  // Per-thread xx fragment: rows j0+4*lane .. +3, all 16 d, pre-scaled.
  // 16 float4 global loads; xx is tiny (256 KB) so these hit L1/L2.
  float4 b[4][4];
  {
    float4 iv[4];
#pragma unroll
    for (int c = 0; c < 4; ++c) iv[c] = *(const float4*)&s_inv[c * 4];
    const int jb = j0 + (lane << 2);
#pragma unroll
    for (int r = 0; r < 4; ++r) {
#pragma unroll
      for (int c = 0; c < 4; ++c) {
        float4 v = *(const float4*)&xx[(jb + r) * DD + c * 4];
        v.x *= iv[c].x; v.y *= iv[c].y; v.z *= iv[c].z; v.w *= iv[c].w;
        b[r][c] = v;
      }
    }
  }

  __syncthreads();  // s_x ready

  const float var = s_var;
  const int jb = j0 + (lane << 2);

#pragma unroll
  for (int ii = 0; ii < 16; ++ii) {
    const int li = wave * 16 + ii;                 // local row in tile
    const float4* a4 = (const float4*)&s_x[li * DD];  // wave-uniform -> LDS broadcast

    float acc0 = 0.f, acc1 = 0.f, acc2 = 0.f, acc3 = 0.f;
#pragma unroll
    for (int c = 0; c < 4; ++c) {
      const float4 a = a4[c];
      float d;
      d = a.x - b[0][c].x; acc0 = fmaf(d, d, acc0);
      d = a.y - b[0][c].y; acc0 = fmaf(d, d, acc0);
      d = a.z - b[0][c].z; acc0 = fmaf(d, d, acc0);
      d = a.w - b[0][c].w; acc0 = fmaf(d, d, acc0);

      d = a.x - b[1][c].x; acc1 = fmaf(d, d, acc1);
      d = a.y - b[1][c].y; acc1 = fmaf(d, d, acc1);
      d = a.z - b[1][c].z; acc1 = fmaf(d, d, acc1);
      d = a.w - b[1][c].w; acc1 = fmaf(d, d, acc1);

      d = a.x - b[2][c].x; acc2 = fmaf(d, d, acc2);
      d = a.y - b[2][c].y; acc2 = fmaf(d, d, acc2);
      d = a.z - b[2][c].z; acc2 = fmaf(d, d, acc2);
      d = a.w - b[2][c].w; acc2 = fmaf(d, d, acc2);

      d = a.x - b[3][c].x; acc3 = fmaf(d, d, acc3);
      d = a.y - b[3][c].y; acc3 = fmaf(d, d, acc3);
      d = a.z - b[3][c].z; acc3 = fmaf(d, d, acc3);
      d = a.w - b[3][c].w; acc3 = fmaf(d, d, acc3);
    }

    float4 o;
    o.x = __expf(-0.5f * acc0) * var;
    o.y = __expf(-0.5f * acc1) * var;
    o.z = __expf(-0.5f * acc2) * var;
    o.w = __expf(-0.5f * acc3) * var;
    *(float4*)&out[(size_t)(i0 + li) * MM + jb] = o;
  }
}

extern "C" void kernel_launch(void* const* d_in, const int* in_sizes, int n_in,
                              void* d_out, int out_size, void* d_ws, size_t ws_size,
                              hipStream_t stream) {
  const float* x   = (const float*)d_in[0];   // [4096,16]
  const float* xx  = (const float*)d_in[1];   // [4096,16]
  const float* sc  = (const float*)d_in[2];   // [16]
  const float* var = (const float*)d_in[3];   // [1]
  float* out = (float*)d_out;                 // [4096,4096]

  dim3 grid(MM / 256, NN / 64);
  dim3 block(256);
  rbf_kernel<<<grid, block, 0, stream>>>(x, xx, sc, var, out);
}

// Round 2
// 90.794 us; speedup vs baseline: 1.0262x; 1.0262x over previous
//
#include <hip/hip_runtime.h>
#include <math.h>

// RBF pairwise kernel: out[i,j] = var * exp(-0.5 * sum_d ((x[i,d]-xx[j,d])/s[d])^2)
// N=M=4096, D=16, fp32 in/out.
//
// R2 change vs R1 (93 us): R1 forced 64 VGPRs of xx-fragment + a fully
// unrolled 16-iter loop under a 128-VGPR launch_bounds cap -> suspected
// scratch spill in the hot loop. Now: 2 j-columns per lane (32 VGPRs of
// fragment), unroll capped at 4, tile 64i x 128j, grid 2048 blocks
// (8192 waves = full wave-slot coverage at 16 waves/CU occupancy).
//
//   - j varies across LANES: lane l owns j = j0 + 2l, 2l+1 -> float2 stores,
//     64 lanes write 512 contiguous bytes per store (fully coalesced).
//   - i is WAVE-UNIFORM: wave w owns i-rows [i0+16w, i0+16w+16). The x-row
//     fragment is read from LDS at one address for all 64 lanes -> broadcast,
//     zero bank conflicts.

#define NN 4096
#define MM 4096
#define DD 16

__global__ __launch_bounds__(256, 4)
void rbf_kernel(const float* __restrict__ x, const float* __restrict__ xx,
                const float* __restrict__ scale_ff,
                const float* __restrict__ variance_ff,
                float* __restrict__ out) {
  __shared__ __align__(16) float s_inv[DD];    // 1/softplus(scale_ff)
  __shared__ float s_var;                      // softplus(variance_ff)
  __shared__ __align__(16) float s_x[64 * DD]; // pre-scaled x tile (64 rows)

  const int tid  = threadIdx.x;
  const int lane = tid & 63;
  const int wave = tid >> 6;

  const int i0 = blockIdx.y * 64;
  const int j0 = blockIdx.x * 128;

  // softplus params (once per block)
  if (tid < DD) {
    s_inv[tid] = 1.0f / log1pf(expf(scale_ff[tid]));
  }
  if (tid == DD) {
    s_var = log1pf(expf(variance_ff[0]));
  }
  __syncthreads();

  // Stage the 64-row x tile into LDS, pre-scaled. 256 threads x 1 float4.
  {
    const int row = tid >> 2;
    const int c   = tid & 3;
    float4 xv = *(const float4*)&x[(i0 + row) * DD + c * 4];
    float4 iv = *(const float4*)&s_inv[c * 4];
    xv.x *= iv.x; xv.y *= iv.y; xv.z *= iv.z; xv.w *= iv.w;
    *(float4*)&s_x[row * DD + c * 4] = xv;
  }

  // Per-lane xx fragment: 2 rows (j0+2*lane, +1), pre-scaled. 32 VGPRs.
  float4 b0[4], b1[4];
  {
    float4 iv[4];
#pragma unroll
    for (int c = 0; c < 4; ++c) iv[c] = *(const float4*)&s_inv[c * 4];
    const int jb = j0 + (lane << 1);
#pragma unroll
    for (int c = 0; c < 4; ++c) {
      float4 v = *(const float4*)&xx[(size_t)jb * DD + c * 4];
      v.x *= iv[c].x; v.y *= iv[c].y; v.z *= iv[c].z; v.w *= iv[c].w;
      b0[c] = v;
      float4 w = *(const float4*)&xx[(size_t)(jb + 1) * DD + c * 4];
      w.x *= iv[c].x; w.y *= iv[c].y; w.z *= iv[c].z; w.w *= iv[c].w;
      b1[c] = w;
    }
  }

  __syncthreads();  // s_x ready

  const float var = s_var;
  const int jb = j0 + (lane << 1);

#pragma unroll 4
  for (int ii = 0; ii < 16; ++ii) {
    const int li = wave * 16 + ii;                    // local row in tile
    const float4* a4 = (const float4*)&s_x[li * DD];  // wave-uniform -> broadcast

    float acc0 = 0.f, acc1 = 0.f;
#pragma unroll
    for (int c = 0; c < 4; ++c) {
      const float4 a = a4[c];
      float d;
      d = a.x - b0[c].x; acc0 = fmaf(d, d, acc0);
      d = a.y - b0[c].y; acc0 = fmaf(d, d, acc0);
      d = a.z - b0[c].z; acc0 = fmaf(d, d, acc0);
      d = a.w - b0[c].w; acc0 = fmaf(d, d, acc0);

      d = a.x - b1[c].x; acc1 = fmaf(d, d, acc1);
      d = a.y - b1[c].y; acc1 = fmaf(d, d, acc1);
      d = a.z - b1[c].z; acc1 = fmaf(d, d, acc1);
      d = a.w - b1[c].w; acc1 = fmaf(d, d, acc1);
    }

    float2 o;
    o.x = __expf(-0.5f * acc0) * var;
    o.y = __expf(-0.5f * acc1) * var;
    *(float2*)&out[(size_t)(i0 + li) * MM + jb] = o;
  }
}

extern "C" void kernel_launch(void* const* d_in, const int* in_sizes, int n_in,
                              void* d_out, int out_size, void* d_ws, size_t ws_size,
                              hipStream_t stream) {
  const float* x   = (const float*)d_in[0];   // [4096,16]
  const float* xx  = (const float*)d_in[1];   // [4096,16]
  const float* sc  = (const float*)d_in[2];   // [16]
  const float* var = (const float*)d_in[3];   // [1]
  float* out = (float*)d_out;                 // [4096,4096]

  dim3 grid(MM / 128, NN / 64);
  dim3 block(256);
  rbf_kernel<<<grid, block, 0, stream>>>(x, xx, sc, var, out);
}

// Round 3
// 90.277 us; speedup vs baseline: 1.0320x; 1.0057x over previous
//
#include <hip/hip_runtime.h>
#include <math.h>

// RBF pairwise kernel: out[i,j] = var * exp(-0.5 * sum_d ((x[i,d]-xx[j,d])/s[d])^2)
// N=M=4096, D=16, fp32 in/out.
//
// R3: algebraic restructure. With a=x/s, b=xx/s:
//   out[i,j] = exp( a_i.b_j - (0.5|a_i|^2 - ln var) - 0.5|b_j|^2 )
// Norms are precomputed once (c_i lives in the LDS row at offset 16; d_j in
// registers), so the hot loop is 16 fma + 2 sub + 1 exp per output (~20
// lane-ops vs 36 in R2). Also 4 j-cols per lane (64i x 256j tile) halves
// LDS-read traffic per output. Exponent t <= ln(var): no overflow possible.
//
//   - j varies across LANES: lane l owns j = j0+4l..+3 -> float4 stores,
//     1 KB contiguous per wave-store, fully coalesced.
//   - i is WAVE-UNIFORM: the a-row (+c) is read from LDS at one address for
//     all 64 lanes -> pure broadcast, zero bank conflicts.

#define NN 4096
#define MM 4096
#define DD 16
#define RS 20   // LDS row stride: 16 data + 1 c + 3 pad (80 B, 16-aligned)

__global__ __launch_bounds__(256, 4)
void rbf_kernel(const float* __restrict__ x, const float* __restrict__ xx,
                const float* __restrict__ scale_ff,
                const float* __restrict__ variance_ff,
                float* __restrict__ out) {
  __shared__ __align__(16) float s_inv[DD];     // 1/softplus(scale_ff)
  __shared__ float s_lnvar;                     // ln(softplus(variance_ff))
  __shared__ __align__(16) float s_a[64 * RS];  // scaled x rows + c_i

  const int tid  = threadIdx.x;
  const int lane = tid & 63;
  const int wave = tid >> 6;

  const int i0 = blockIdx.y * 64;
  const int j0 = blockIdx.x * 256;

  if (tid < DD) {
    s_inv[tid] = 1.0f / log1pf(expf(scale_ff[tid]));
  }
  if (tid == DD) {
    s_lnvar = logf(log1pf(expf(variance_ff[0])));
  }
  __syncthreads();

  // Stage scaled x tile (64 rows) into LDS. 256 threads x 1 float4.
  {
    const int row = tid >> 2;
    const int c   = tid & 3;
    float4 xv = *(const float4*)&x[(i0 + row) * DD + c * 4];
    float4 iv = *(const float4*)&s_inv[c * 4];
    xv.x *= iv.x; xv.y *= iv.y; xv.z *= iv.z; xv.w *= iv.w;
    *(float4*)&s_a[row * RS + c * 4] = xv;
  }
  __syncthreads();

  // c_i = 0.5*|a_i|^2 - ln(var), one thread per row (once per block).
  if (tid < 64) {
    float s = 0.f;
#pragma unroll
    for (int c = 0; c < 4; ++c) {
      float4 v = *(const float4*)&s_a[tid * RS + c * 4];
      s = fmaf(v.x, v.x, s); s = fmaf(v.y, v.y, s);
      s = fmaf(v.z, v.z, s); s = fmaf(v.w, v.w, s);
    }
    s_a[tid * RS + DD] = 0.5f * s - s_lnvar;
  }

  // Per-lane xx fragment: 4 rows (j0+4*lane..+3), scaled, + 0.5*|b|^2.
  float4 b[4][4];
  float dn[4];
  {
    float4 iv[4];
#pragma unroll
    for (int c = 0; c < 4; ++c) iv[c] = *(const float4*)&s_inv[c * 4];
    const int jb = j0 + (lane << 2);
#pragma unroll
    for (int r = 0; r < 4; ++r) {
      float s = 0.f;
#pragma unroll
      for (int c = 0; c < 4; ++c) {
        float4 v = *(const float4*)&xx[(size_t)(jb + r) * DD + c * 4];
        v.x *= iv[c].x; v.y *= iv[c].y; v.z *= iv[c].z; v.w *= iv[c].w;
        b[r][c] = v;
        s = fmaf(v.x, v.x, s); s = fmaf(v.y, v.y, s);
        s = fmaf(v.z, v.z, s); s = fmaf(v.w, v.w, s);
      }
      dn[r] = 0.5f * s;
    }
  }

  __syncthreads();  // s_a (rows + c) ready

  const int jb = j0 + (lane << 2);

#pragma unroll 2
  for (int ii = 0; ii < 16; ++ii) {
    const int li = wave * 16 + ii;                    // local row in tile
    const float* ap = &s_a[li * RS];                  // wave-uniform -> broadcast
    const float4 a0 = *(const float4*)&ap[0];
    const float4 a1 = *(const float4*)&ap[4];
    const float4 a2 = *(const float4*)&ap[8];
    const float4 a3 = *(const float4*)&ap[12];
    const float cc  = ap[DD];

    float acc[4] = {0.f, 0.f, 0.f, 0.f};
#pragma unroll
    for (int r = 0; r < 4; ++r) {
      float s = 0.f;
      s = fmaf(a0.x, b[r][0].x, s); s = fmaf(a0.y, b[r][0].y, s);
      s = fmaf(a0.z, b[r][0].z, s); s = fmaf(a0.w, b[r][0].w, s);
      s = fmaf(a1.x, b[r][1].x, s); s = fmaf(a1.y, b[r][1].y, s);
      s = fmaf(a1.z, b[r][1].z, s); s = fmaf(a1.w, b[r][1].w, s);
      s = fmaf(a2.x, b[r][2].x, s); s = fmaf(a2.y, b[r][2].y, s);
      s = fmaf(a2.z, b[r][2].z, s); s = fmaf(a2.w, b[r][2].w, s);
      s = fmaf(a3.x, b[r][3].x, s); s = fmaf(a3.y, b[r][3].y, s);
      s = fmaf(a3.z, b[r][3].z, s); s = fmaf(a3.w, b[r][3].w, s);
      acc[r] = s;
    }

    float4 o;
    o.x = __expf(acc[0] - cc - dn[0]);
    o.y = __expf(acc[1] - cc - dn[1]);
    o.z = __expf(acc[2] - cc - dn[2]);
    o.w = __expf(acc[3] - cc - dn[3]);
    *(float4*)&out[(size_t)(i0 + li) * MM + jb] = o;
  }
}

extern "C" void kernel_launch(void* const* d_in, const int* in_sizes, int n_in,
                              void* d_out, int out_size, void* d_ws, size_t ws_size,
                              hipStream_t stream) {
  const float* x   = (const float*)d_in[0];   // [4096,16]
  const float* xx  = (const float*)d_in[1];   // [4096,16]
  const float* sc  = (const float*)d_in[2];   // [16]
  const float* var = (const float*)d_in[3];   // [1]
  float* out = (float*)d_out;                 // [4096,4096]

  dim3 grid(MM / 256, NN / 64);
  dim3 block(256);
  rbf_kernel<<<grid, block, 0, stream>>>(x, xx, sc, var, out);
}